// Round 1
// baseline (487.467 us; speedup 1.0000x reference)
//
#include <hip/hip_runtime.h>
#include <hip/hip_bf16.h>

typedef __attribute__((ext_vector_type(8))) __bf16 bf16x8;
typedef __attribute__((ext_vector_type(4))) float  f32x4;

#define NTOK   8192
#define DMODEL 1024
#define HDIM   4096
#define NEXP   8

// ------------------------------------------------------------------ utils
__global__ void zero_cnt_kernel(int* cnt) {
  if (threadIdx.x < NEXP) cnt[threadIdx.x] = 0;
}

// ------------------------------------------------------------------ gating
// One wave per token. logits = x . gate_w + gate_b ; softmax ; top-2 ;
// chosen expert = max index of top-2 (reference's where() overwrite order);
// weight = softmax score of chosen expert. Scatter token into expert list.
__global__ __launch_bounds__(256) void moe_gate_kernel(
    const float* __restrict__ x, const float* __restrict__ gw,
    const float* __restrict__ gb, float* __restrict__ wst,
    int* __restrict__ cnt, int* __restrict__ lists)
{
  const int lane = threadIdx.x & 63;
  const int wv   = threadIdx.x >> 6;
  const int t    = (blockIdx.x << 2) + wv;
  const float* xp = x + (size_t)t * DMODEL;

  float acc[NEXP];
#pragma unroll
  for (int e = 0; e < NEXP; ++e) acc[e] = 0.f;

#pragma unroll
  for (int j = 0; j < DMODEL / 64; ++j) {
    const int d = (j << 6) + lane;
    const float xv = xp[d];
    const float4 g0 = *(const float4*)(gw + (size_t)d * NEXP);
    const float4 g1 = *(const float4*)(gw + (size_t)d * NEXP + 4);
    acc[0] = fmaf(xv, g0.x, acc[0]);
    acc[1] = fmaf(xv, g0.y, acc[1]);
    acc[2] = fmaf(xv, g0.z, acc[2]);
    acc[3] = fmaf(xv, g0.w, acc[3]);
    acc[4] = fmaf(xv, g1.x, acc[4]);
    acc[5] = fmaf(xv, g1.y, acc[5]);
    acc[6] = fmaf(xv, g1.z, acc[6]);
    acc[7] = fmaf(xv, g1.w, acc[7]);
  }
#pragma unroll
  for (int e = 0; e < NEXP; ++e) {
#pragma unroll
    for (int off = 32; off > 0; off >>= 1)
      acc[e] += __shfl_xor(acc[e], off, 64);
  }
  if (lane == 0) {
    float l[NEXP];
#pragma unroll
    for (int e = 0; e < NEXP; ++e) l[e] = acc[e] + gb[e];
    // top-1 (strict > : lower index wins ties, matching top_k)
    int i1 = 0; float m1 = l[0];
#pragma unroll
    for (int e = 1; e < NEXP; ++e) if (l[e] > m1) { m1 = l[e]; i1 = e; }
    // top-2
    int i2 = -1; float m2 = -3.402823466e38f;
#pragma unroll
    for (int e = 0; e < NEXP; ++e) if (e != i1 && l[e] > m2) { m2 = l[e]; i2 = e; }
    const int es = i1 > i2 ? i1 : i2;    // reference: last expert in loop wins
    float s = 0.f;
#pragma unroll
    for (int e = 0; e < NEXP; ++e) s += expf(l[e] - m1);
    const float w = expf(l[es] - m1) / s;
    wst[t] = w;
    const int pos = atomicAdd(&cnt[es], 1);
    lists[(size_t)es * NTOK + pos] = t;
  }
}

// ------------------------------------------------------------------ GEMM1
// H[token][h] = relu( (x[token]*w*) @ w1[e] + b1[e] ), bf16 output.
// 128x128 tile, BK=32, 4 waves (2x2 of 64x64), mfma 16x16x32 bf16.
// A,B staged in LDS as [row][k] with k contiguous, row stride padded to 40
// elems (80B) -> <=2-way bank aliasing on ds_read_b128 (free).
__global__ __launch_bounds__(256) void moe_gemm1_kernel(
    const float* __restrict__ x, const float* __restrict__ w1,
    const float* __restrict__ b1, const float* __restrict__ wst,
    const int* __restrict__ cnt, const int* __restrict__ lists,
    __bf16* __restrict__ hmat)
{
  const int e  = blockIdx.z;
  const int ce = cnt[e];
  const int m0 = blockIdx.y << 7;
  if (m0 >= ce) return;
  const int n0 = blockIdx.x << 7;
  const int* list = lists + (size_t)e * NTOK;

  const int tid  = threadIdx.x;
  const int lane = tid & 63;
  const int wv   = tid >> 6;
  const int wr   = (wv >> 1) << 6;   // wave row offset in tile
  const int wc   = (wv & 1) << 6;    // wave col offset in tile

  __shared__ alignas(16) __bf16 As[128][40];
  __shared__ alignas(16) __bf16 Bs[128][40];

  // A staging: 2 threads per row, each 16 consecutive k
  const int arow = tid >> 1;
  const int ak   = (tid & 1) << 4;
  const int am   = m0 + arow;
  const bool valid_a = am < ce;
  const int atok = valid_a ? list[am] : 0;
  const float ascale = valid_a ? wst[atok] : 0.0f;
  const float* ap = x + (size_t)atok * DMODEL + ak;

  // B staging: thread owns one output column h, 16 consecutive k (stride-H
  // column loads; lanes have consecutive h -> coalesced 256B segments).
  const int bh = tid & 127;
  const int bk = (tid >> 7) << 4;
  const float* bp = w1 + (size_t)e * (DMODEL * (size_t)HDIM) + (size_t)(n0 + bh);

  f32x4 acc[4][4] = {};
  float ar[16], br[16];

  auto loadA = [&](int k) {
    const float4 v0 = *(const float4*)(ap + k);
    const float4 v1 = *(const float4*)(ap + k + 4);
    const float4 v2 = *(const float4*)(ap + k + 8);
    const float4 v3 = *(const float4*)(ap + k + 12);
    ar[0]=v0.x;  ar[1]=v0.y;  ar[2]=v0.z;  ar[3]=v0.w;
    ar[4]=v1.x;  ar[5]=v1.y;  ar[6]=v1.z;  ar[7]=v1.w;
    ar[8]=v2.x;  ar[9]=v2.y;  ar[10]=v2.z; ar[11]=v2.w;
    ar[12]=v3.x; ar[13]=v3.y; ar[14]=v3.z; ar[15]=v3.w;
  };
  auto loadB = [&](int k) {
#pragma unroll
    for (int j = 0; j < 16; ++j) br[j] = bp[(size_t)(k + bk + j) * HDIM];
  };

  loadA(0); loadB(0);
  for (int k0 = 0; k0 < DMODEL; k0 += 32) {
    __syncthreads();
    bf16x8 pa0, pa1, pb0, pb1;
#pragma unroll
    for (int j = 0; j < 8; ++j) {
      pa0[j] = (__bf16)(ar[j] * ascale);
      pa1[j] = (__bf16)(ar[j + 8] * ascale);
      pb0[j] = (__bf16)br[j];
      pb1[j] = (__bf16)br[j + 8];
    }
    *(bf16x8*)&As[arow][ak]     = pa0;
    *(bf16x8*)&As[arow][ak + 8] = pa1;
    *(bf16x8*)&Bs[bh][bk]       = pb0;
    *(bf16x8*)&Bs[bh][bk + 8]   = pb1;
    __syncthreads();
    if (k0 + 32 < DMODEL) { loadA(k0 + 32); loadB(k0 + 32); }  // prefetch

    const int rl = lane & 15;
    const int kh = (lane >> 4) << 3;
    bf16x8 af[4], bfv[4];
#pragma unroll
    for (int f = 0; f < 4; ++f) af[f]  = *(const bf16x8*)&As[wr + f*16 + rl][kh];
#pragma unroll
    for (int f = 0; f < 4; ++f) bfv[f] = *(const bf16x8*)&Bs[wc + f*16 + rl][kh];
#pragma unroll
    for (int i = 0; i < 4; ++i)
#pragma unroll
      for (int j = 0; j < 4; ++j)
        acc[i][j] = __builtin_amdgcn_mfma_f32_16x16x32_bf16(af[i], bfv[j], acc[i][j], 0, 0, 0);
  }

  // epilogue: bias + relu -> bf16, scatter rows by token id
  const int cl = lane & 15;
  const int rh = (lane >> 4) << 2;
  float bb[4];
#pragma unroll
  for (int j = 0; j < 4; ++j) bb[j] = b1[(size_t)e * HDIM + n0 + wc + j*16 + cl];
#pragma unroll
  for (int i = 0; i < 4; ++i) {
#pragma unroll
    for (int r = 0; r < 4; ++r) {
      const int gm = m0 + wr + i*16 + rh + r;
      if (gm < ce) {
        const int tok = list[gm];
        __bf16* op = hmat + (size_t)tok * HDIM + n0 + wc;
#pragma unroll
        for (int j = 0; j < 4; ++j) {
          float v = acc[i][j][r] + bb[j];
          v = fmaxf(v, 0.f);
          op[j*16 + cl] = (__bf16)v;
        }
      }
    }
  }
}

// ------------------------------------------------------------------ GEMM2
// out[token][d] = H[token] @ w2[e] + b2[e], fp32 output. Same structure,
// K = 4096, A already bf16.
__global__ __launch_bounds__(256) void moe_gemm2_kernel(
    const __bf16* __restrict__ hmat, const float* __restrict__ w2,
    const float* __restrict__ b2, const int* __restrict__ cnt,
    const int* __restrict__ lists, float* __restrict__ out)
{
  const int e  = blockIdx.z;
  const int ce = cnt[e];
  const int m0 = blockIdx.y << 7;
  if (m0 >= ce) return;
  const int n0 = blockIdx.x << 7;
  const int* list = lists + (size_t)e * NTOK;

  const int tid  = threadIdx.x;
  const int lane = tid & 63;
  const int wv   = tid >> 6;
  const int wr   = (wv >> 1) << 6;
  const int wc   = (wv & 1) << 6;

  __shared__ alignas(16) __bf16 As[128][40];
  __shared__ alignas(16) __bf16 Bs[128][40];

  const int arow = tid >> 1;
  const int ak   = (tid & 1) << 4;
  const int am   = m0 + arow;
  const bool valid_a = am < ce;
  const int atok = valid_a ? list[am] : 0;
  const __bf16* ap = hmat + (size_t)atok * HDIM + ak;

  const int bh = tid & 127;
  const int bk = (tid >> 7) << 4;
  const float* bp = w2 + (size_t)e * ((size_t)HDIM * DMODEL) + (size_t)(n0 + bh);

  f32x4 acc[4][4] = {};
  bf16x8 ar0, ar1;
#pragma unroll
  for (int j = 0; j < 8; ++j) { ar0[j] = (__bf16)0.f; ar1[j] = (__bf16)0.f; }
  float br[16];

  auto loadA = [&](int k) {
    if (valid_a) {
      ar0 = *(const bf16x8*)(ap + k);
      ar1 = *(const bf16x8*)(ap + k + 8);
    }
  };
  auto loadB = [&](int k) {
#pragma unroll
    for (int j = 0; j < 16; ++j) br[j] = bp[(size_t)(k + bk + j) * DMODEL];
  };

  loadA(0); loadB(0);
  for (int k0 = 0; k0 < HDIM; k0 += 32) {
    __syncthreads();
    bf16x8 pb0, pb1;
#pragma unroll
    for (int j = 0; j < 8; ++j) {
      pb0[j] = (__bf16)br[j];
      pb1[j] = (__bf16)br[j + 8];
    }
    *(bf16x8*)&As[arow][ak]     = ar0;
    *(bf16x8*)&As[arow][ak + 8] = ar1;
    *(bf16x8*)&Bs[bh][bk]       = pb0;
    *(bf16x8*)&Bs[bh][bk + 8]   = pb1;
    __syncthreads();
    if (k0 + 32 < HDIM) { loadA(k0 + 32); loadB(k0 + 32); }  // prefetch

    const int rl = lane & 15;
    const int kh = (lane >> 4) << 3;
    bf16x8 af[4], bfv[4];
#pragma unroll
    for (int f = 0; f < 4; ++f) af[f]  = *(const bf16x8*)&As[wr + f*16 + rl][kh];
#pragma unroll
    for (int f = 0; f < 4; ++f) bfv[f] = *(const bf16x8*)&Bs[wc + f*16 + rl][kh];
#pragma unroll
    for (int i = 0; i < 4; ++i)
#pragma unroll
      for (int j = 0; j < 4; ++j)
        acc[i][j] = __builtin_amdgcn_mfma_f32_16x16x32_bf16(af[i], bfv[j], acc[i][j], 0, 0, 0);
  }

  const int cl = lane & 15;
  const int rh = (lane >> 4) << 2;
  float bb[4];
#pragma unroll
  for (int j = 0; j < 4; ++j) bb[j] = b2[(size_t)e * DMODEL + n0 + wc + j*16 + cl];
#pragma unroll
  for (int i = 0; i < 4; ++i) {
#pragma unroll
    for (int r = 0; r < 4; ++r) {
      const int gm = m0 + wr + i*16 + rh + r;
      if (gm < ce) {
        const int tok = list[gm];
        float* op = out + (size_t)tok * DMODEL + n0 + wc;
#pragma unroll
        for (int j = 0; j < 4; ++j)
          op[j*16 + cl] = acc[i][j][r] + bb[j];
      }
    }
  }
}

// ------------------------------------------------------------------ launch
extern "C" void kernel_launch(void* const* d_in, const int* in_sizes, int n_in,
                              void* d_out, int out_size, void* d_ws, size_t ws_size,
                              hipStream_t stream)
{
  const float* x  = (const float*)d_in[0];
  const float* gw = (const float*)d_in[1];
  const float* gb = (const float*)d_in[2];
  const float* w1 = (const float*)d_in[3];
  const float* b1 = (const float*)d_in[4];
  const float* w2 = (const float*)d_in[5];
  const float* b2 = (const float*)d_in[6];
  float* out = (float*)d_out;

  char* ws = (char*)d_ws;
  int*    cnt   = (int*)ws;                   // 8 ints
  float*  wst   = (float*)(ws + 1024);        // per-token gate weight
  int*    lists = (int*)(ws + 65536);         // 8 x 8192 token ids (256 KB)
  __bf16* hmat  = (__bf16*)(ws + (1 << 20));  // 8192 x 4096 bf16 (64 MB)

  zero_cnt_kernel<<<1, 64, 0, stream>>>(cnt);
  moe_gate_kernel<<<NTOK / 4, 256, 0, stream>>>(x, gw, gb, wst, cnt, lists);
  moe_gemm1_kernel<<<dim3(HDIM / 128, NTOK / 128, NEXP), 256, 0, stream>>>(
      x, w1, b1, wst, cnt, lists, hmat);
  moe_gemm2_kernel<<<dim3(DMODEL / 128, NTOK / 128, NEXP), 256, 0, stream>>>(
      hmat, w2, b2, cnt, lists, out);
}

// Round 2
// 437.920 us; speedup vs baseline: 1.1131x; 1.1131x over previous
//
#include <hip/hip_runtime.h>
#include <hip/hip_bf16.h>
#include <stdint.h>

typedef __attribute__((ext_vector_type(8))) __bf16 bf16x8;
typedef __attribute__((ext_vector_type(4))) __bf16 bf16x4;
typedef __attribute__((ext_vector_type(4))) float  f32x4;

#define NTOK   8192
#define DMODEL 1024
#define HDIM   4096
#define NEXP   8

__device__ __forceinline__ void glds16(const void* g, void* l) {
  __builtin_amdgcn_global_load_lds(
      (const __attribute__((address_space(1))) uint32_t*)g,
      (__attribute__((address_space(3))) uint32_t*)l, 16, 0, 0);
}

// ------------------------------------------------------------------ utils
__global__ void zero_cnt_kernel(int* cnt) {
  if (threadIdx.x < NEXP) cnt[threadIdx.x] = 0;
}

// ------------------------------------------------------------------ gating
__global__ __launch_bounds__(256) void moe_gate_kernel(
    const float* __restrict__ x, const float* __restrict__ gw,
    const float* __restrict__ gb, float* __restrict__ wst,
    int* __restrict__ cnt, int* __restrict__ lists)
{
  const int lane = threadIdx.x & 63;
  const int wv   = threadIdx.x >> 6;
  const int t    = (blockIdx.x << 2) + wv;
  const float* xp = x + (size_t)t * DMODEL;

  float acc[NEXP];
#pragma unroll
  for (int e = 0; e < NEXP; ++e) acc[e] = 0.f;

#pragma unroll
  for (int j = 0; j < DMODEL / 64; ++j) {
    const int d = (j << 6) + lane;
    const float xv = xp[d];
    const float4 g0 = *(const float4*)(gw + (size_t)d * NEXP);
    const float4 g1 = *(const float4*)(gw + (size_t)d * NEXP + 4);
    acc[0] = fmaf(xv, g0.x, acc[0]);
    acc[1] = fmaf(xv, g0.y, acc[1]);
    acc[2] = fmaf(xv, g0.z, acc[2]);
    acc[3] = fmaf(xv, g0.w, acc[3]);
    acc[4] = fmaf(xv, g1.x, acc[4]);
    acc[5] = fmaf(xv, g1.y, acc[5]);
    acc[6] = fmaf(xv, g1.z, acc[6]);
    acc[7] = fmaf(xv, g1.w, acc[7]);
  }
#pragma unroll
  for (int e = 0; e < NEXP; ++e) {
#pragma unroll
    for (int off = 32; off > 0; off >>= 1)
      acc[e] += __shfl_xor(acc[e], off, 64);
  }
  if (lane == 0) {
    float l[NEXP];
#pragma unroll
    for (int e = 0; e < NEXP; ++e) l[e] = acc[e] + gb[e];
    int i1 = 0; float m1 = l[0];
#pragma unroll
    for (int e = 1; e < NEXP; ++e) if (l[e] > m1) { m1 = l[e]; i1 = e; }
    int i2 = -1; float m2 = -3.402823466e38f;
#pragma unroll
    for (int e = 0; e < NEXP; ++e) if (e != i1 && l[e] > m2) { m2 = l[e]; i2 = e; }
    const int es = i1 > i2 ? i1 : i2;    // reference: last expert in loop wins
    float s = 0.f;
#pragma unroll
    for (int e = 0; e < NEXP; ++e) s += expf(l[e] - m1);
    const float w = expf(l[es] - m1) / s;
    wst[t] = w;
    const int pos = atomicAdd(&cnt[es], 1);
    lists[(size_t)es * NTOK + pos] = t;
  }
}

// ------------------------------------------------------------------ pack x
// xbf[t][d] = bf16(x[t][d] * wst[t])  (same rounding point as r1's staging)
__global__ __launch_bounds__(256) void pack_x_kernel(
    const float* __restrict__ x, const float* __restrict__ wst,
    __bf16* __restrict__ xbf)
{
  const int t = blockIdx.x;
  const float w = wst[t];
  const int d = threadIdx.x * 4;
  const float4 v = *(const float4*)(x + (size_t)t * DMODEL + d);
  bf16x4 o;
  o[0] = (__bf16)(v.x * w); o[1] = (__bf16)(v.y * w);
  o[2] = (__bf16)(v.z * w); o[3] = (__bf16)(v.w * w);
  *(bf16x4*)(xbf + (size_t)t * DMODEL + d) = o;
}

// ------------------------------------------------------------------ pack W
// Pack src [NEXP][K][N] fp32 into bf16 tiles of 128 cols x 64 k, laid out as
// the exact (XOR-swizzled) LDS image so global_load_lds stages them linearly.
// Tile byte (n*128 + slot*16 + j*2) holds src[ks*64 + (slot^(n&7))*8 + j][n].
template<int N, int KS_PER>
__global__ __launch_bounds__(256) void pack_w_kernel(
    const float* __restrict__ src, __bf16* __restrict__ dst)
{
  const int ks = blockIdx.x, np = blockIdx.y, e = blockIdx.z;
  const int K = KS_PER * 64;
  const int tid = threadIdx.x;
  const int n  = tid >> 1;            // 0..127 (tile-local col)
  const int sh = (tid & 1) * 4;       // slot half: 0 or 4
  const float* sp = src + (size_t)e * K * N + (size_t)(np * 128 + n);
  __bf16* dp = dst + (((size_t)e * (N / 128) + np) * KS_PER + ks) * 8192
                   + n * 64 + sh * 8;
  const int swz = n & 7;
#pragma unroll
  for (int s = 0; s < 4; ++s) {
    const int slot = sh + s;
    const int kofs = (slot ^ swz) * 8;
    bf16x8 v;
#pragma unroll
    for (int j = 0; j < 8; ++j)
      v[j] = (__bf16)sp[(size_t)(ks * 64 + kofs + j) * N];
    *(bf16x8*)(dp + s * 8) = v;
  }
}

// ------------------------------------------------------------------ GEMM
// C[token][n] = A[token] @ Bpacked[e] + bias[e], token rows from expert list.
// 128x128 tile, BK=64, 4 waves, all staging via global_load_lds (16B),
// double-buffered LDS with counted s_waitcnt vmcnt(8) (loads span barriers).
template<int KSTEPS, int ASTRIDE, int NOUT, bool RELU, typename OutT>
__global__ __launch_bounds__(256, 2) void moe_gemm_kernel(
    const __bf16* __restrict__ Am, const __bf16* __restrict__ Bp,
    const float* __restrict__ bias, const int* __restrict__ cnt,
    const int* __restrict__ lists, OutT* __restrict__ outp)
{
  const int e  = blockIdx.z;
  const int ce = cnt[e];
  const int m0 = blockIdx.y << 7;
  if (m0 >= ce) return;
  const int np = blockIdx.x;
  const int n0 = np << 7;
  const int* list = lists + (size_t)e * NTOK;

  const int tid = threadIdx.x, lane = tid & 63, wv = tid >> 6;
  const int wr = (wv >> 1) << 6, wc = (wv & 1) << 6;

  // [buf][ A 8192 elems | B 8192 elems ]  x2 buffers = 64 KiB
  __shared__ alignas(16) __bf16 lds[32768];

  // per-lane A source chunks (4 x 16B per wave-quarter); row/slot fixed
  int atok[4], akof[4];
#pragma unroll
  for (int i = 0; i < 4; ++i) {
    const int cid = wv * 256 + i * 64 + lane;   // chunk id in 128x64 tile
    const int row = cid >> 3, slot = cid & 7;
    const int rm  = m0 + row;
    atok[i] = list[rm < ce ? rm : ce - 1];
    akof[i] = (slot ^ (row & 7)) * 8;           // swizzle-adjusted k offset
  }
  const __bf16* btile = Bp + ((size_t)e * (NOUT / 128) + np) * (size_t)KSTEPS * 8192
                           + wv * 2048 + lane * 8;

  const int cl = lane & 15, rh = (lane >> 4) << 2;
  float bb[4];
#pragma unroll
  for (int j = 0; j < 4; ++j) bb[j] = bias[(size_t)e * NOUT + n0 + wc + j * 16 + cl];

  auto stage = [&](int buf, int ks) {
    __bf16* Ad = lds + buf * 16384 + wv * 2048;
    __bf16* Bd = Ad + 8192;
#pragma unroll
    for (int i = 0; i < 4; ++i)
      glds16(Am + (size_t)atok[i] * ASTRIDE + ks * 64 + akof[i], Ad + i * 512);
    const __bf16* bt = btile + (size_t)ks * 8192;
#pragma unroll
    for (int i = 0; i < 4; ++i)
      glds16(bt + i * 512, Bd + i * 512);
  };

  f32x4 acc[4][4] = {};
  const int rl = lane & 15;
  const int sb = (lane >> 4) * 16;

  stage(0, 0);
  int cur = 0;
  for (int ks = 0; ks < KSTEPS; ++ks) {
    if (ks + 1 < KSTEPS) {
      stage(cur ^ 1, ks + 1);                       // 8 loads stay in flight
      asm volatile("s_waitcnt vmcnt(8)" ::: "memory");
    } else {
      asm volatile("s_waitcnt vmcnt(0)" ::: "memory");
    }
    __builtin_amdgcn_sched_barrier(0);
    __builtin_amdgcn_s_barrier();                   // current buf fully staged
    __builtin_amdgcn_sched_barrier(0);

    const __bf16* Asl = lds + cur * 16384;
    const __bf16* Bsl = Asl + 8192;
#pragma unroll
    for (int kk = 0; kk < 2; ++kk) {
      bf16x8 af[4], bfv[4];
#pragma unroll
      for (int f = 0; f < 4; ++f) {
        const int r = wr + f * 16 + rl;
        af[f] = *(const bf16x8*)((const char*)(Asl + r * 64) +
                                 ((kk * 64 + sb) ^ ((r & 7) << 4)));
      }
#pragma unroll
      for (int f = 0; f < 4; ++f) {
        const int r = wc + f * 16 + rl;
        bfv[f] = *(const bf16x8*)((const char*)(Bsl + r * 64) +
                                  ((kk * 64 + sb) ^ ((r & 7) << 4)));
      }
#pragma unroll
      for (int i = 0; i < 4; ++i)
#pragma unroll
        for (int j = 0; j < 4; ++j)
          acc[i][j] = __builtin_amdgcn_mfma_f32_16x16x32_bf16(af[i], bfv[j], acc[i][j], 0, 0, 0);
    }
    __builtin_amdgcn_sched_barrier(0);
    __builtin_amdgcn_s_barrier();                   // all waves done reading cur
    asm volatile("" ::: "memory");
    cur ^= 1;
  }

  // epilogue: bias (+relu) and scatter by token id
#pragma unroll
  for (int i = 0; i < 4; ++i) {
#pragma unroll
    for (int r = 0; r < 4; ++r) {
      const int gm = m0 + wr + i * 16 + rh + r;
      if (gm < ce) {
        const int tok = list[gm];
        OutT* op = outp + (size_t)tok * NOUT + n0 + wc;
#pragma unroll
        for (int j = 0; j < 4; ++j) {
          float v = acc[i][j][r] + bb[j];
          if constexpr (RELU) v = fmaxf(v, 0.f);
          op[j * 16 + cl] = (OutT)v;
        }
      }
    }
  }
}

// ======================================================= r1 fallback GEMMs
__global__ __launch_bounds__(256) void moe_gemm1_kernel(
    const float* __restrict__ x, const float* __restrict__ w1,
    const float* __restrict__ b1, const float* __restrict__ wst,
    const int* __restrict__ cnt, const int* __restrict__ lists,
    __bf16* __restrict__ hmat)
{
  const int e  = blockIdx.z;
  const int ce = cnt[e];
  const int m0 = blockIdx.y << 7;
  if (m0 >= ce) return;
  const int n0 = blockIdx.x << 7;
  const int* list = lists + (size_t)e * NTOK;
  const int tid  = threadIdx.x;
  const int lane = tid & 63;
  const int wv   = tid >> 6;
  const int wr   = (wv >> 1) << 6;
  const int wc   = (wv & 1) << 6;
  __shared__ alignas(16) __bf16 As[128][40];
  __shared__ alignas(16) __bf16 Bs[128][40];
  const int arow = tid >> 1;
  const int ak   = (tid & 1) << 4;
  const int am   = m0 + arow;
  const bool valid_a = am < ce;
  const int atok = valid_a ? list[am] : 0;
  const float ascale = valid_a ? wst[atok] : 0.0f;
  const float* ap = x + (size_t)atok * DMODEL + ak;
  const int bh = tid & 127;
  const int bk = (tid >> 7) << 4;
  const float* bp = w1 + (size_t)e * (DMODEL * (size_t)HDIM) + (size_t)(n0 + bh);
  f32x4 acc[4][4] = {};
  float ar[16], br[16];
  auto loadA = [&](int k) {
    const float4 v0 = *(const float4*)(ap + k);
    const float4 v1 = *(const float4*)(ap + k + 4);
    const float4 v2 = *(const float4*)(ap + k + 8);
    const float4 v3 = *(const float4*)(ap + k + 12);
    ar[0]=v0.x;  ar[1]=v0.y;  ar[2]=v0.z;  ar[3]=v0.w;
    ar[4]=v1.x;  ar[5]=v1.y;  ar[6]=v1.z;  ar[7]=v1.w;
    ar[8]=v2.x;  ar[9]=v2.y;  ar[10]=v2.z; ar[11]=v2.w;
    ar[12]=v3.x; ar[13]=v3.y; ar[14]=v3.z; ar[15]=v3.w;
  };
  auto loadB = [&](int k) {
#pragma unroll
    for (int j = 0; j < 16; ++j) br[j] = bp[(size_t)(k + bk + j) * HDIM];
  };
  loadA(0); loadB(0);
  for (int k0 = 0; k0 < DMODEL; k0 += 32) {
    __syncthreads();
    bf16x8 pa0, pa1, pb0, pb1;
#pragma unroll
    for (int j = 0; j < 8; ++j) {
      pa0[j] = (__bf16)(ar[j] * ascale);
      pa1[j] = (__bf16)(ar[j + 8] * ascale);
      pb0[j] = (__bf16)br[j];
      pb1[j] = (__bf16)br[j + 8];
    }
    *(bf16x8*)&As[arow][ak]     = pa0;
    *(bf16x8*)&As[arow][ak + 8] = pa1;
    *(bf16x8*)&Bs[bh][bk]       = pb0;
    *(bf16x8*)&Bs[bh][bk + 8]   = pb1;
    __syncthreads();
    if (k0 + 32 < DMODEL) { loadA(k0 + 32); loadB(k0 + 32); }
    const int rl = lane & 15;
    const int kh = (lane >> 4) << 3;
    bf16x8 af[4], bfv[4];
#pragma unroll
    for (int f = 0; f < 4; ++f) af[f]  = *(const bf16x8*)&As[wr + f*16 + rl][kh];
#pragma unroll
    for (int f = 0; f < 4; ++f) bfv[f] = *(const bf16x8*)&Bs[wc + f*16 + rl][kh];
#pragma unroll
    for (int i = 0; i < 4; ++i)
#pragma unroll
      for (int j = 0; j < 4; ++j)
        acc[i][j] = __builtin_amdgcn_mfma_f32_16x16x32_bf16(af[i], bfv[j], acc[i][j], 0, 0, 0);
  }
  const int cl = lane & 15;
  const int rh = (lane >> 4) << 2;
  float bb[4];
#pragma unroll
  for (int j = 0; j < 4; ++j) bb[j] = b1[(size_t)e * HDIM + n0 + wc + j*16 + cl];
#pragma unroll
  for (int i = 0; i < 4; ++i) {
#pragma unroll
    for (int r = 0; r < 4; ++r) {
      const int gm = m0 + wr + i*16 + rh + r;
      if (gm < ce) {
        const int tok = list[gm];
        __bf16* op = hmat + (size_t)tok * HDIM + n0 + wc;
#pragma unroll
        for (int j = 0; j < 4; ++j) {
          float v = acc[i][j][r] + bb[j];
          v = fmaxf(v, 0.f);
          op[j*16 + cl] = (__bf16)v;
        }
      }
    }
  }
}

__global__ __launch_bounds__(256) void moe_gemm2_kernel(
    const __bf16* __restrict__ hmat, const float* __restrict__ w2,
    const float* __restrict__ b2, const int* __restrict__ cnt,
    const int* __restrict__ lists, float* __restrict__ out)
{
  const int e  = blockIdx.z;
  const int ce = cnt[e];
  const int m0 = blockIdx.y << 7;
  if (m0 >= ce) return;
  const int n0 = blockIdx.x << 7;
  const int* list = lists + (size_t)e * NTOK;
  const int tid  = threadIdx.x;
  const int lane = tid & 63;
  const int wv   = tid >> 6;
  const int wr   = (wv >> 1) << 6;
  const int wc   = (wv & 1) << 6;
  __shared__ alignas(16) __bf16 As[128][40];
  __shared__ alignas(16) __bf16 Bs[128][40];
  const int arow = tid >> 1;
  const int ak   = (tid & 1) << 4;
  const int am   = m0 + arow;
  const bool valid_a = am < ce;
  const int atok = valid_a ? list[am] : 0;
  const __bf16* ap = hmat + (size_t)atok * HDIM + ak;
  const int bh = tid & 127;
  const int bk = (tid >> 7) << 4;
  const float* bp = w2 + (size_t)e * ((size_t)HDIM * DMODEL) + (size_t)(n0 + bh);
  f32x4 acc[4][4] = {};
  bf16x8 ar0, ar1;
#pragma unroll
  for (int j = 0; j < 8; ++j) { ar0[j] = (__bf16)0.f; ar1[j] = (__bf16)0.f; }
  float br[16];
  auto loadA = [&](int k) {
    if (valid_a) {
      ar0 = *(const bf16x8*)(ap + k);
      ar1 = *(const bf16x8*)(ap + k + 8);
    }
  };
  auto loadB = [&](int k) {
#pragma unroll
    for (int j = 0; j < 16; ++j) br[j] = bp[(size_t)(k + bk + j) * DMODEL];
  };
  loadA(0); loadB(0);
  for (int k0 = 0; k0 < HDIM; k0 += 32) {
    __syncthreads();
    bf16x8 pb0, pb1;
#pragma unroll
    for (int j = 0; j < 8; ++j) {
      pb0[j] = (__bf16)br[j];
      pb1[j] = (__bf16)br[j + 8];
    }
    *(bf16x8*)&As[arow][ak]     = ar0;
    *(bf16x8*)&As[arow][ak + 8] = ar1;
    *(bf16x8*)&Bs[bh][bk]       = pb0;
    *(bf16x8*)&Bs[bh][bk + 8]   = pb1;
    __syncthreads();
    if (k0 + 32 < HDIM) { loadA(k0 + 32); loadB(k0 + 32); }
    const int rl = lane & 15;
    const int kh = (lane >> 4) << 3;
    bf16x8 af[4], bfv[4];
#pragma unroll
    for (int f = 0; f < 4; ++f) af[f]  = *(const bf16x8*)&As[wr + f*16 + rl][kh];
#pragma unroll
    for (int f = 0; f < 4; ++f) bfv[f] = *(const bf16x8*)&Bs[wc + f*16 + rl][kh];
#pragma unroll
    for (int i = 0; i < 4; ++i)
#pragma unroll
      for (int j = 0; j < 4; ++j)
        acc[i][j] = __builtin_amdgcn_mfma_f32_16x16x32_bf16(af[i], bfv[j], acc[i][j], 0, 0, 0);
  }
  const int cl = lane & 15;
  const int rh = (lane >> 4) << 2;
  float bb[4];
#pragma unroll
  for (int j = 0; j < 4; ++j) bb[j] = b2[(size_t)e * DMODEL + n0 + wc + j*16 + cl];
#pragma unroll
  for (int i = 0; i < 4; ++i) {
#pragma unroll
    for (int r = 0; r < 4; ++r) {
      const int gm = m0 + wr + i*16 + rh + r;
      if (gm < ce) {
        const int tok = list[gm];
        float* op = out + (size_t)tok * DMODEL + n0 + wc;
#pragma unroll
        for (int j = 0; j < 4; ++j)
          op[j*16 + cl] = acc[i][j][r] + bb[j];
      }
    }
  }
}

// ------------------------------------------------------------------ launch
extern "C" void kernel_launch(void* const* d_in, const int* in_sizes, int n_in,
                              void* d_out, int out_size, void* d_ws, size_t ws_size,
                              hipStream_t stream)
{
  const float* x  = (const float*)d_in[0];
  const float* gw = (const float*)d_in[1];
  const float* gb = (const float*)d_in[2];
  const float* w1 = (const float*)d_in[3];
  const float* b1 = (const float*)d_in[4];
  const float* w2 = (const float*)d_in[5];
  const float* b2 = (const float*)d_in[6];
  float* out = (float*)d_out;

  char* ws = (char*)d_ws;
  int*    cnt   = (int*)ws;                         // 32 B
  float*  wst   = (float*)(ws + 1024);              // 32 KB
  int*    lists = (int*)(ws + 65536);               // 256 KB

  if (ws_size >= ((size_t)209 << 20)) {
    __bf16* xbf  = (__bf16*)(ws + ((size_t)1   << 20));   // 16 MB
    __bf16* hmat = (__bf16*)(ws + ((size_t)17  << 20));   // 64 MB
    __bf16* w1p  = (__bf16*)(ws + ((size_t)81  << 20));   // 64 MB
    __bf16* w2p  = (__bf16*)(ws + ((size_t)145 << 20));   // 64 MB

    zero_cnt_kernel<<<1, 64, 0, stream>>>(cnt);
    pack_w_kernel<HDIM, 16><<<dim3(16, 32, NEXP), 256, 0, stream>>>(w1, w1p);
    pack_w_kernel<DMODEL, 64><<<dim3(64, 8, NEXP), 256, 0, stream>>>(w2, w2p);
    moe_gate_kernel<<<NTOK / 4, 256, 0, stream>>>(x, gw, gb, wst, cnt, lists);
    pack_x_kernel<<<NTOK, 256, 0, stream>>>(x, wst, xbf);
    moe_gemm_kernel<16, DMODEL, HDIM, true, __bf16>
        <<<dim3(HDIM / 128, 64, NEXP), 256, 0, stream>>>(xbf, w1p, b1, cnt, lists, hmat);
    moe_gemm_kernel<64, HDIM, DMODEL, false, float>
        <<<dim3(DMODEL / 128, 64, NEXP), 256, 0, stream>>>(hmat, w2p, b2, cnt, lists, out);
  } else {
    __bf16* hmat = (__bf16*)(ws + (1 << 20));
    zero_cnt_kernel<<<1, 64, 0, stream>>>(cnt);
    moe_gate_kernel<<<NTOK / 4, 256, 0, stream>>>(x, gw, gb, wst, cnt, lists);
    moe_gemm1_kernel<<<dim3(HDIM / 128, NTOK / 128, NEXP), 256, 0, stream>>>(
        x, w1, b1, wst, cnt, lists, hmat);
    moe_gemm2_kernel<<<dim3(DMODEL / 128, NTOK / 128, NEXP), 256, 0, stream>>>(
        hmat, w2, b2, cnt, lists, out);
  }
}